// Round 14
// baseline (73.476 us; speedup 1.0000x reference)
//
#include <hip/hip_runtime.h>
#include <hip/hip_bf16.h>
#include <stdint.h>

#define NROWS 4096
#define DIMS  2048
#define BM    256
#define BKB   64              // K-tile = 64 int8 = 64 B rows
#define NTILES (DIMS / BKB)   // 32
#define NTB   (NROWS / BM)    // 16 -> 256 blocks
#define MARGIN_F 0.3f

typedef __attribute__((ext_vector_type(4))) int   i32x4;
typedef __attribute__((ext_vector_type(4))) float f32x4;

__device__ inline void atomicMaxF(float* addr, float v) {
  if (v >= 0.f) atomicMax((int*)addr, __float_as_int(v));
  else          atomicMin((unsigned int*)addr, __float_as_uint(v));
}
__device__ inline void atomicMinF(float* addr, float v) {
  if (v >= 0.f) atomicMin((int*)addr, __float_as_int(v));
  else          atomicMax((unsigned int*)addr, __float_as_uint(v));
}

__device__ inline void load_lds16(const void* g, void* l) {
  __builtin_amdgcn_global_load_lds(
      (const __attribute__((address_space(1))) void*)(g),
      (__attribute__((address_space(3))) void*)(l), 16, 0, 0);
}

// ------- normalize + per-row int8 quantization (q = rint(x*127/amax)) -------
__global__ __launch_bounds__(256) void norm_kernel(const float* __restrict__ in,
                                                   char* __restrict__ l2q,
                                                   float* __restrict__ recip,
                                                   float* __restrict__ dap,
                                                   float* __restrict__ dan) {
  int row = blockIdx.x;
  int t = threadIdx.x;
  const float4* rin = (const float4*)(in + (size_t)row * DIMS);
  float4 v0 = rin[t];
  float4 v1 = rin[t + 256];
  float ss = v0.x*v0.x + v0.y*v0.y + v0.z*v0.z + v0.w*v0.w
           + v1.x*v1.x + v1.y*v1.y + v1.z*v1.z + v1.w*v1.w;
  float am = fmaxf(fmaxf(fmaxf(fabsf(v0.x), fabsf(v0.y)), fmaxf(fabsf(v0.z), fabsf(v0.w))),
                   fmaxf(fmaxf(fabsf(v1.x), fabsf(v1.y)), fmaxf(fabsf(v1.z), fabsf(v1.w))));
  #pragma unroll
  for (int s = 1; s < 64; s <<= 1) {
    ss += __shfl_xor(ss, s);
    am = fmaxf(am, __shfl_xor(am, s));
  }
  __shared__ float wsum[4], wmax[4];
  if ((t & 63) == 0) { wsum[t >> 6] = ss; wmax[t >> 6] = am; }
  __syncthreads();
  float tot = wsum[0] + wsum[1] + wsum[2] + wsum[3];
  float amax = fmaxf(fmaxf(wmax[0], wmax[1]), fmaxf(wmax[2], wmax[3]));
  float rn = 1.0f / sqrtf(tot);
  float qs = 127.0f / amax;
  int q0 = (int)rintf(v0.x * qs), q1 = (int)rintf(v0.y * qs);
  int q2 = (int)rintf(v0.z * qs), q3 = (int)rintf(v0.w * qs);
  int q4 = (int)rintf(v1.x * qs), q5 = (int)rintf(v1.y * qs);
  int q6 = (int)rintf(v1.z * qs), q7 = (int)rintf(v1.w * qs);
  int p0 = (q0 & 255) | ((q1 & 255) << 8) | ((q2 & 255) << 16) | (q3 << 24);
  int p1 = (q4 & 255) | ((q5 & 255) << 8) | ((q6 & 255) << 16) | (q7 << 24);
  int* orow = (int*)(l2q + (size_t)row * DIMS);
  orow[t] = p0;
  orow[t + 256] = p1;
  if (t == 0) {
    recip[row] = amax * rn / 127.0f;
    dap[row] = -__builtin_inff();
    dan[row] = __builtin_inff();
  }
}

// ---------------- fused int8 GEMM (acc = Q . Q^T) + masked row max/min ----------------
// r12 structure with PREFETCH DEPTH 3 (the A/B test): 4 LDS sets x 32 KB =
// 128 KB; prologue stages tiles 0-2; loop stages t+3; gate vmcnt(8) drains
// exactly tile t's 4 loads, issued 3 tile-times (~13k cy) earlier.
// Theory under test: per-tile time ~4500 cy is exposed global->LDS latency
// at depth 2 (T = L/2); depth 3 -> T = max(interior ~1500, L/3).
// All addressing/swizzle/epilogue byte-identical to r12 (verified absmax 0).
__global__ __launch_bounds__(512) void gemm_reduce_kernel(
    const char* __restrict__ l2q, const int* __restrict__ tgt,
    const float* __restrict__ recip,
    float* __restrict__ dap, float* __restrict__ dan) {
  __shared__ __attribute__((aligned(16))) char ldsbuf[131072];  // 4 x (16K A + 16K B)

  // XCD-chunked bijective swizzle (256 blocks, 8 XCDs -> 32 contiguous per XCD)
  int c = blockIdx.x;
  int swz = (c & 7) * 32 + (c >> 3);
  int bi = swz >> 4, bj = swz & 15;

  int tid = threadIdx.x;
  int lane = tid & 63, w = tid >> 6;
  int wr = w >> 2;        // 0..1  (M half: 128 rows)
  int nc = w & 3;         // 0..3  (N quarter: 64 cols)

  i32x4 acc[8][4];
  #pragma unroll
  for (int m = 0; m < 8; m++)
    #pragma unroll
    for (int n = 0; n < 4; n++) acc[m][n] = (i32x4){0, 0, 0, 0};

  // --- staging source (r9/r12-identical verified pattern) ---
  int srow = tid >> 2;                               // 0..127
  int qq = (tid & 3) ^ ((tid >> 3) & 3);
  const char* gA = l2q + ((size_t)(bi * BM + srow)) * DIMS + qq * 16;
  const char* gB = l2q + ((size_t)(bj * BM + srow)) * DIMS + qq * 16;

  // --- fragment read offsets (bytes; verified zero-conflict swizzle) ---
  int laneq = lane & 15, g = lane >> 4;
  int fcB = (g ^ ((laneq >> 1) & 3)) * 16;           // swizzled 16B chunk slot
  int aOffB = (wr * 128 + laneq) * 64 + fcB;
  int bOffB = 16384 + (nc * 64 + laneq) * 64 + fcB;

  i32x4 aU[4], aV[4], bR[4];

  #define STAGE_A(T, DOFF)                                                    \
    do {                                                                      \
      load_lds16(gA + (size_t)(T) * 64, &ldsbuf[(DOFF) + w * 1024]);          \
      load_lds16(gA + (size_t)128 * DIMS + (size_t)(T) * 64,                  \
                 &ldsbuf[(DOFF) + 8192 + w * 1024]);                          \
    } while (0)
  #define STAGE_B(T, DOFF)                                                    \
    do {                                                                      \
      load_lds16(gB + (size_t)(T) * 64, &ldsbuf[(DOFF) + 16384 + w * 1024]);  \
      load_lds16(gB + (size_t)128 * DIMS + (size_t)(T) * 64,                  \
                 &ldsbuf[(DOFF) + 24576 + w * 1024]);                         \
    } while (0)

  #define READ_A4(DST, MB, COFF)                                              \
    _Pragma("unroll")                                                         \
    for (int m = 0; m < 4; m++)                                               \
      DST[m] = *(const i32x4*)&ldsbuf[(COFF) + aOffB + ((MB) + m) * 1024];
  #define READ_B4(DST, COFF)                                                  \
    _Pragma("unroll")                                                         \
    for (int n = 0; n < 4; n++)                                               \
      DST[n] = *(const i32x4*)&ldsbuf[(COFF) + bOffB + n * 1024];

  #define MFMA16(MB, AR, BR)                                                  \
    __builtin_amdgcn_s_setprio(1);                                            \
    _Pragma("unroll")                                                         \
    for (int m = 0; m < 4; m++)                                               \
      _Pragma("unroll")                                                       \
      for (int n = 0; n < 4; n++)                                             \
        acc[(MB) + m][n] = __builtin_amdgcn_mfma_i32_16x16x64_i8(             \
            AR[m], BR[n], acc[(MB) + m][n], 0, 0, 0);                         \
    __builtin_amdgcn_s_setprio(0);

  #define SB __builtin_amdgcn_sched_barrier(0);

  #define TILE_BODY(CUR)                                                      \
    do {                                                                      \
      READ_B4(bR, CUR)                                                        \
      READ_A4(aU, 0, CUR)                                                     \
      MFMA16(0, aU, bR)                                                       \
      READ_A4(aV, 4, CUR)                                                     \
      MFMA16(4, aV, bR)                                                       \
    } while (0)

  #define GATE(N)                                                             \
    asm volatile("s_waitcnt vmcnt(" #N ")" ::: "memory");                     \
    SB                                                                        \
    __builtin_amdgcn_s_barrier();                                             \
    SB

  // prologue: stage tiles 0,1,2 into sets 0,1,2 (FIFO = gate drain order)
  STAGE_A(0, 0);
  STAGE_B(0, 0);
  STAGE_A(1, 32768);
  STAGE_B(1, 32768);
  STAGE_A(2, 65536);
  STAGE_B(2, 65536);

  // steady state: tiles 0..28 stage t+3 (depth 3); 12 loads in flight.
  int curOff = 0, dstOff = 98304;
  #pragma unroll 1
  for (int kt = 0; kt < NTILES - 3; ++kt) {
    GATE(8)                                            // drain tile kt's 4 loads
    STAGE_A(kt + 3, dstOff);
    STAGE_B(kt + 3, dstOff);
    TILE_BODY(curOff);
    curOff = (curOff + 32768) & 131071;
    dstOff = (dstOff + 32768) & 131071;
  }
  // tile 29: 12 outstanding, no staging
  GATE(8)
  TILE_BODY(curOff);
  curOff = (curOff + 32768) & 131071;
  // tile 30: 8 outstanding
  GATE(4)
  TILE_BODY(curOff);
  curOff = (curOff + 32768) & 131071;
  // tile 31: drain
  GATE(0)
  TILE_BODY(curOff);

  // ---- fused masked reduction (r12-identical) ----
  // acc[m][n][r] = Gq[bi*256 + wr*128 + m*16 + g*4 + r]
  //                  [bj*256 + nc*64  + n*16 + laneq]
  int tcol[4];
  float tcr[4];
  #pragma unroll
  for (int n = 0; n < 4; n++) {
    int idx = bj * BM + nc * 64 + n * 16 + laneq;
    tcol[n] = tgt[idx];
    tcr[n] = recip[idx];
  }
  int rbase = bi * BM + wr * 128 + g * 4;

  #pragma unroll
  for (int m = 0; m < 8; m++) {
    #pragma unroll
    for (int r = 0; r < 4; r++) {
      int grow = rbase + m * 16 + r;
      int trow = tgt[grow];
      float rrw = recip[grow];
      float ap = -__builtin_inff(), an = __builtin_inff();
      #pragma unroll
      for (int n = 0; n < 4; n++) {
        float d = -(float)acc[m][n][r] * rrw * tcr[n];
        bool same = (trow == tcol[n]);
        ap = same ? fmaxf(ap, d) : ap;
        an = same ? an : fminf(an, d);
      }
      #pragma unroll
      for (int s = 1; s < 16; s <<= 1) {
        ap = fmaxf(ap, __shfl_xor(ap, s));
        an = fminf(an, __shfl_xor(an, s));
      }
      if (laneq == 0) {
        atomicMaxF(&dap[grow], ap);
        atomicMinF(&dan[grow], an);
      }
    }
  }
  #undef STAGE_A
  #undef STAGE_B
  #undef READ_A4
  #undef READ_B4
  #undef MFMA16
  #undef SB
  #undef TILE_BODY
  #undef GATE
}

// ---------------- final loss ----------------
__global__ __launch_bounds__(256) void loss_kernel(const float* __restrict__ dap,
                                                   const float* __restrict__ dan,
                                                   float* __restrict__ out) {
  int t = threadIdx.x;
  float s = 0.f;
  for (int i = t; i < NROWS; i += 256) {
    float v = dap[i] - dan[i] + MARGIN_F;
    s += v > 0.f ? v : 0.f;
  }
  #pragma unroll
  for (int sh = 1; sh < 64; sh <<= 1) s += __shfl_xor(s, sh);
  __shared__ float ws[4];
  if ((t & 63) == 0) ws[t >> 6] = s;
  __syncthreads();
  if (t == 0) out[0] = (ws[0] + ws[1] + ws[2] + ws[3]) * (1.0f / (float)NROWS);
}

extern "C" void kernel_launch(void* const* d_in, const int* in_sizes, int n_in,
                              void* d_out, int out_size, void* d_ws, size_t ws_size,
                              hipStream_t stream) {
  const float* inputs = (const float*)d_in[0];
  const int* targets = (const int*)d_in[1];
  char* l2q = (char*)d_ws;
  float* recip = (float*)((char*)d_ws + (size_t)NROWS * DIMS);
  float* dap = recip + NROWS;
  float* dan = dap + NROWS;
  float* out = (float*)d_out;

  hipLaunchKernelGGL(norm_kernel, dim3(NROWS), dim3(256), 0, stream,
                     inputs, l2q, recip, dap, dan);
  hipLaunchKernelGGL(gemm_reduce_kernel, dim3(NTB * NTB), dim3(512), 0, stream,
                     l2q, targets, recip, dap, dan);
  hipLaunchKernelGGL(loss_kernel, dim3(1), dim3(256), 0, stream, dap, dan, out);
}